// Round 6
// baseline (100.470 us; speedup 1.0000x reference)
//
#include <hip/hip_runtime.h>
#include <math.h>

// ListwiseSmoothINDCGKLoss: bs x ll (16384 x 2048) fp32 scores + graded labels
// -> scalar sum(1 - ndcg@10).
//
// Structure: ONE WAVE OWNS ONE ROW (EPT=32), 4 independent waves per
// 256-thread block -> zero __syncthreads, zero LDS. Per-k reduction is a
// 6-step DPP add (row_shr:1,2,4,8 + row_bcast:15,31 -> total in lane 63),
// pure VALU, then v_readlane broadcast.
//
// Round-6 change: __launch_bounds__(256, 4) -> VGPR cap 128. Round 5 used
// (256,3) and the compiler chose 72 VGPRs: persistent w[32]+q[32]=64 live,
// so e[32] was REMATERIALIZED (exp2 recomputed in the prod update) -- +32
// transcendentals/k/lane, ~40% extra issue. HW occupancy bins halve at
// VGPR=64/128/256, so 72 and ~112 are the SAME occupancy (4 waves/SIMD);
// giving the compiler the full 128 keeps e in registers at zero cost.
//
// Carried lessons:
//  - NO local arrays (rounds 2-3: scratch allocas -> GBs of spill traffic);
//    every per-element value is a named scalar via macro expansion.
//  - scale-invariant softmax: exact row max not needed, M_k = min(range,118)*0.9^k
//    is a safe upper bound (row-min of z is 0, |prod|<=0.9^k). No per-k max.
//  - IDCG closed-form from packed label histogram (labels are ints 0..4).
//  - no divides in the loop: v_rcp + reciprocal-log2 constants.

constexpr int LL      = 2048;
constexpr int THREADS = 256;  // 4 waves; wave w handles row blockIdx*4+w
constexpr int RPB     = 4;
constexpr int KTOP    = 10;
constexpr float ALPHA  = 10.0f;
constexpr float EPSF   = 1e-10f;
constexpr float LOG2E  = 1.44269504088896340736f;
constexpr float MCLAMP = 118.0f;

// 1 / log2(k+2), k = 0..9 (constexpr + unroll-constant index => immediates)
__device__ constexpr float INVDEN[KTOP] = {
    1.0f,                 0.6309297535714574f, 0.5f,                0.43067655807339306f,
    0.38685280723454163f, 0.356207187108022f,  0.3333333333333333f, 0.31546487678572877f,
    0.30102999566398114f, 0.2890648263178878f};

// ---- DPP wave64 reductions (result lands in lane 63) ----
template <int CTRL>
__device__ __forceinline__ float dpp_addf(float v) {
    return v + __int_as_float(__builtin_amdgcn_update_dpp(
                   0, __float_as_int(v), CTRL, 0xF, 0xF, false));
}
template <int CTRL>
__device__ __forceinline__ float dpp_minf(float v) {
    return fminf(v, __int_as_float(__builtin_amdgcn_update_dpp(
                        0x7F800000, __float_as_int(v), CTRL, 0xF, 0xF, false)));
}
template <int CTRL>
__device__ __forceinline__ float dpp_maxf(float v) {
    return fmaxf(v, __int_as_float(__builtin_amdgcn_update_dpp(
                        (int)0xFF800000, __float_as_int(v), CTRL, 0xF, 0xF, false)));
}
template <int CTRL>
__device__ __forceinline__ int dpp_addi(int v) {
    return v + __builtin_amdgcn_update_dpp(0, v, CTRL, 0xF, 0xF, false);
}

// row_shr:1,2,4,8 then row_bcast:15, row_bcast:31
#define WAVE_RED(OP, v)                                                     \
    v = OP<0x111>(v); v = OP<0x112>(v); v = OP<0x114>(v); v = OP<0x118>(v); \
    v = OP<0x142>(v); v = OP<0x143>(v);

__device__ __forceinline__ float rl63f(float v) {
    return __int_as_float(__builtin_amdgcn_readlane(__float_as_int(v), 63));
}

// chunk expander: 8 chunks x 4 scalars = 32 elements per lane
#define CH(F) F(0) F(1) F(2) F(3) F(4) F(5) F(6) F(7)

__global__ __launch_bounds__(THREADS, 4) void ndcg_loss_kernel(
    const float* __restrict__ s, const float* __restrict__ label,
    float* __restrict__ ws, float* __restrict__ out, int mode) {
    const int    lane = threadIdx.x & 63;
    const int    wave = threadIdx.x >> 6;
    const size_t row  = (size_t)blockIdx.x * RPB + wave;

    const float4* sp = (const float4*)(s + row * (size_t)LL);
    const float4* lp = (const float4*)(label + row * (size_t)LL);

    // coalesced loads: chunk c = 1 KB contiguous (64 lanes x 16 B)
#define LOADS(c) const float4 sA##c = sp[(c) * 64 + lane];
    CH(LOADS)
#define LOADL(c) const float4 qA##c = lp[(c) * 64 + lane];
    CH(LOADL)

    // ---- row min / max ----
    float mn = sA0.x, mx = sA0.x;
#define MM(c)                                                                  \
    mn = fminf(mn, fminf(fminf(sA##c.x, sA##c.y), fminf(sA##c.z, sA##c.w)));   \
    mx = fmaxf(mx, fmaxf(fmaxf(sA##c.x, sA##c.y), fmaxf(sA##c.z, sA##c.w)));
    CH(MM)
    WAVE_RED(dpp_minf, mn)
    WAVE_RED(dpp_maxf, mx)
    mn = rl63f(mn);
    mx = rl63f(mx);

    // ---- packed label histogram: hA = c0|c1<<16, hB = c2|c3<<16, hC = c4 ----
    int hA = 0, hB = 0, hC = 0;
#define H1(q)                                   \
    {                                           \
        const int li = (int)(q);                \
        hA += (li == 0) + ((li == 1) << 16);    \
        hB += (li == 2) + ((li == 3) << 16);    \
        hC += (li == 4);                        \
    }
#define HC(c) H1(qA##c.x) H1(qA##c.y) H1(qA##c.z) H1(qA##c.w)
    CH(HC)
    WAVE_RED(dpp_addi, hA)
    WAVE_RED(dpp_addi, hB)
    WAVE_RED(dpp_addi, hC)
    hA = __builtin_amdgcn_readlane(hA, 63);
    hB = __builtin_amdgcn_readlane(hB, 63);
    hC = __builtin_amdgcn_readlane(hC, 63);

    const int n4 = hC;
    const int n3 = n4 + (hB >> 16);
    const int n2 = n3 + (hB & 0xFFFF);
    const int n1 = n2 + (hA >> 16);
    float idcg = EPSF;
#pragma unroll
    for (int slot = 0; slot < KTOP; ++slot) {
        const int v = (slot < n4) + (slot < n3) + (slot < n2) + (slot < n1);
        idcg = fmaf((float)(1 << v), INVDEN[slot], idcg);
    }

    // ---- w = z*prod, initialized to z = (s - mn)*ALPHA*log2(e) ----
    const float Cc = ALPHA * LOG2E;
#define WD(c)                                                        \
    float w##c##x = (sA##c.x - mn) * Cc, w##c##y = (sA##c.y - mn) * Cc, \
          w##c##z = (sA##c.z - mn) * Cc, w##c##w = (sA##c.w - mn) * Cc;
    CH(WD)
    float M   = fminf((mx - mn) * Cc, MCLAMP);
    float dcg = EPSF;

#pragma unroll
    for (int k = 0; k < KTOP; ++k) {
#define ED(c)                                                  \
    const float e##c##x = __builtin_amdgcn_exp2f(w##c##x - M), \
                e##c##y = __builtin_amdgcn_exp2f(w##c##y - M), \
                e##c##z = __builtin_amdgcn_exp2f(w##c##z - M), \
                e##c##w = __builtin_amdgcn_exp2f(w##c##w - M);
        CH(ED)
        float se = 0.0f, sle = 0.0f;
#define AC(c)                                                       \
    se += (e##c##x + e##c##y) + (e##c##z + e##c##w);                \
    sle += fmaf(qA##c.x, e##c##x, qA##c.y * e##c##y) +              \
           fmaf(qA##c.z, e##c##z, qA##c.w * e##c##w);
        CH(AC)
        WAVE_RED(dpp_addf, se)
        WAVE_RED(dpp_addf, sle)
        se  = rl63f(se);
        sle = rl63f(sle);

        const float inv = __builtin_amdgcn_rcpf(se);
        dcg = fmaf(__builtin_amdgcn_exp2f(sle * inv), INVDEN[k], dcg);

        // w' = w * (0.9 - e*inv)   [prod update folded into w]
#define UP(c)                                \
    w##c##x *= fmaf(e##c##x, -inv, 0.9f);    \
    w##c##y *= fmaf(e##c##y, -inv, 0.9f);    \
    w##c##z *= fmaf(e##c##z, -inv, 0.9f);    \
    w##c##w *= fmaf(e##c##w, -inv, 0.9f);
        CH(UP)
        M *= 0.9f;
    }

    if (lane == 0) {
        const float loss = 1.0f - dcg / idcg;
        if (mode) atomicAdd(out, loss);
        else      ws[row] = loss;
    }
}

__global__ __launch_bounds__(256) void reduce_sum_kernel(
    const float* __restrict__ w, float* __restrict__ out, int n4) {
    __shared__ float sb[4];
    float acc = 0.0f;
    const float4* w4 = (const float4*)w;
    for (int i = threadIdx.x; i < n4; i += 256) {
        const float4 v = w4[i];
        acc += (v.x + v.y) + (v.z + v.w);
    }
#pragma unroll
    for (int o = 32; o; o >>= 1) acc += __shfl_xor(acc, o, 64);
    if ((threadIdx.x & 63) == 0) sb[threadIdx.x >> 6] = acc;
    __syncthreads();
    if (threadIdx.x == 0) out[0] = (sb[0] + sb[1]) + (sb[2] + sb[3]);
}

__global__ void zero_out_kernel(float* out) { out[0] = 0.0f; }

extern "C" void kernel_launch(void* const* d_in, const int* in_sizes, int n_in,
                              void* d_out, int out_size, void* d_ws,
                              size_t ws_size, hipStream_t stream) {
    const float* s     = (const float*)d_in[0];
    const float* label = (const float*)d_in[1];
    float*       out   = (float*)d_out;
    const int    bs    = in_sizes[0] / LL;

    if ((bs % RPB) == 0 && ws_size >= (size_t)bs * sizeof(float)) {
        float* w = (float*)d_ws;
        ndcg_loss_kernel<<<bs / RPB, THREADS, 0, stream>>>(s, label, w, nullptr, 0);
        reduce_sum_kernel<<<1, 256, 0, stream>>>(w, out, bs / 4);
    } else {
        zero_out_kernel<<<1, 1, 0, stream>>>(out);
        ndcg_loss_kernel<<<bs / RPB, THREADS, 0, stream>>>(s, label, nullptr, out, 1);
    }
}

// Round 7
// 90.405 us; speedup vs baseline: 1.1113x; 1.1113x over previous
//
#include <hip/hip_runtime.h>
#include <math.h>

// ListwiseSmoothINDCGKLoss: bs x ll (16384 x 2048) fp32 scores + graded labels
// -> scalar sum(1 - ndcg@10).
//
// Structure: ONE WAVE OWNS ONE ROW (EPT=32), 4 independent waves per
// 256-thread block -> zero __syncthreads, zero LDS. Per-k reduction is a
// 6-step DPP add (row_shr:1,2,4,8 + row_bcast:15,31 -> total in lane 63),
// pure VALU, then v_readlane broadcast.
//
// Round-7 change: __launch_bounds__(256, 2). Calibration from rounds 5/6:
// the backend's VGPR cap behaves as ~256/min_waves_per_EU:
//   min=3 -> cap ~85 (chose 72, remat'd e[:32]: +32 exp2/k/lane, 89.7 us)
//   min=4 -> cap 64  (61 MB scratch spills, 100.5 us)
// min=2 -> cap 128 lets the full live set (w32+q32+e32+misc ~ 112) stay
// register-resident. HW occupancy at ~112 VGPR is the same 4-waves/SIMD bin
// as at 72 (bins halve at 64/128/256), so this costs nothing real.
//
// Carried lessons:
//  - NO local arrays (rounds 2-3: scratch allocas -> GBs of spill traffic);
//    every per-element value is a named scalar via macro expansion.
//  - scale-invariant softmax: exact row max not needed, M_k = min(range,118)*0.9^k
//    is a safe upper bound (row-min of z is 0, |prod|<=0.9^k). No per-k max.
//  - IDCG closed-form from packed label histogram (labels are ints 0..4).
//  - no divides in the loop: v_rcp + reciprocal-log2 constants.

constexpr int LL      = 2048;
constexpr int THREADS = 256;  // 4 waves; wave w handles row blockIdx*4+w
constexpr int RPB     = 4;
constexpr int KTOP    = 10;
constexpr float ALPHA  = 10.0f;
constexpr float EPSF   = 1e-10f;
constexpr float LOG2E  = 1.44269504088896340736f;
constexpr float MCLAMP = 118.0f;

// 1 / log2(k+2), k = 0..9 (constexpr + unroll-constant index => immediates)
__device__ constexpr float INVDEN[KTOP] = {
    1.0f,                 0.6309297535714574f, 0.5f,                0.43067655807339306f,
    0.38685280723454163f, 0.356207187108022f,  0.3333333333333333f, 0.31546487678572877f,
    0.30102999566398114f, 0.2890648263178878f};

// ---- DPP wave64 reductions (result lands in lane 63) ----
template <int CTRL>
__device__ __forceinline__ float dpp_addf(float v) {
    return v + __int_as_float(__builtin_amdgcn_update_dpp(
                   0, __float_as_int(v), CTRL, 0xF, 0xF, false));
}
template <int CTRL>
__device__ __forceinline__ float dpp_minf(float v) {
    return fminf(v, __int_as_float(__builtin_amdgcn_update_dpp(
                        0x7F800000, __float_as_int(v), CTRL, 0xF, 0xF, false)));
}
template <int CTRL>
__device__ __forceinline__ float dpp_maxf(float v) {
    return fmaxf(v, __int_as_float(__builtin_amdgcn_update_dpp(
                        (int)0xFF800000, __float_as_int(v), CTRL, 0xF, 0xF, false)));
}
template <int CTRL>
__device__ __forceinline__ int dpp_addi(int v) {
    return v + __builtin_amdgcn_update_dpp(0, v, CTRL, 0xF, 0xF, false);
}

// row_shr:1,2,4,8 then row_bcast:15, row_bcast:31
#define WAVE_RED(OP, v)                                                     \
    v = OP<0x111>(v); v = OP<0x112>(v); v = OP<0x114>(v); v = OP<0x118>(v); \
    v = OP<0x142>(v); v = OP<0x143>(v);

__device__ __forceinline__ float rl63f(float v) {
    return __int_as_float(__builtin_amdgcn_readlane(__float_as_int(v), 63));
}

// chunk expander: 8 chunks x 4 scalars = 32 elements per lane
#define CH(F) F(0) F(1) F(2) F(3) F(4) F(5) F(6) F(7)

__global__ __launch_bounds__(THREADS, 2) void ndcg_loss_kernel(
    const float* __restrict__ s, const float* __restrict__ label,
    float* __restrict__ ws, float* __restrict__ out, int mode) {
    const int    lane = threadIdx.x & 63;
    const int    wave = threadIdx.x >> 6;
    const size_t row  = (size_t)blockIdx.x * RPB + wave;

    const float4* sp = (const float4*)(s + row * (size_t)LL);
    const float4* lp = (const float4*)(label + row * (size_t)LL);

    // coalesced loads: chunk c = 1 KB contiguous (64 lanes x 16 B)
#define LOADS(c) const float4 sA##c = sp[(c) * 64 + lane];
    CH(LOADS)
#define LOADL(c) const float4 qA##c = lp[(c) * 64 + lane];
    CH(LOADL)

    // ---- row min / max ----
    float mn = sA0.x, mx = sA0.x;
#define MM(c)                                                                  \
    mn = fminf(mn, fminf(fminf(sA##c.x, sA##c.y), fminf(sA##c.z, sA##c.w)));   \
    mx = fmaxf(mx, fmaxf(fmaxf(sA##c.x, sA##c.y), fmaxf(sA##c.z, sA##c.w)));
    CH(MM)
    WAVE_RED(dpp_minf, mn)
    WAVE_RED(dpp_maxf, mx)
    mn = rl63f(mn);
    mx = rl63f(mx);

    // ---- packed label histogram: hA = c0|c1<<16, hB = c2|c3<<16, hC = c4 ----
    int hA = 0, hB = 0, hC = 0;
#define H1(q)                                   \
    {                                           \
        const int li = (int)(q);                \
        hA += (li == 0) + ((li == 1) << 16);    \
        hB += (li == 2) + ((li == 3) << 16);    \
        hC += (li == 4);                        \
    }
#define HC(c) H1(qA##c.x) H1(qA##c.y) H1(qA##c.z) H1(qA##c.w)
    CH(HC)
    WAVE_RED(dpp_addi, hA)
    WAVE_RED(dpp_addi, hB)
    WAVE_RED(dpp_addi, hC)
    hA = __builtin_amdgcn_readlane(hA, 63);
    hB = __builtin_amdgcn_readlane(hB, 63);
    hC = __builtin_amdgcn_readlane(hC, 63);

    const int n4 = hC;
    const int n3 = n4 + (hB >> 16);
    const int n2 = n3 + (hB & 0xFFFF);
    const int n1 = n2 + (hA >> 16);
    float idcg = EPSF;
#pragma unroll
    for (int slot = 0; slot < KTOP; ++slot) {
        const int v = (slot < n4) + (slot < n3) + (slot < n2) + (slot < n1);
        idcg = fmaf((float)(1 << v), INVDEN[slot], idcg);
    }

    // ---- w = z*prod, initialized to z = (s - mn)*ALPHA*log2(e) ----
    const float Cc = ALPHA * LOG2E;
#define WD(c)                                                        \
    float w##c##x = (sA##c.x - mn) * Cc, w##c##y = (sA##c.y - mn) * Cc, \
          w##c##z = (sA##c.z - mn) * Cc, w##c##w = (sA##c.w - mn) * Cc;
    CH(WD)
    float M   = fminf((mx - mn) * Cc, MCLAMP);
    float dcg = EPSF;

#pragma unroll
    for (int k = 0; k < KTOP; ++k) {
#define ED(c)                                                  \
    const float e##c##x = __builtin_amdgcn_exp2f(w##c##x - M), \
                e##c##y = __builtin_amdgcn_exp2f(w##c##y - M), \
                e##c##z = __builtin_amdgcn_exp2f(w##c##z - M), \
                e##c##w = __builtin_amdgcn_exp2f(w##c##w - M);
        CH(ED)
        float se = 0.0f, sle = 0.0f;
#define AC(c)                                                       \
    se += (e##c##x + e##c##y) + (e##c##z + e##c##w);                \
    sle += fmaf(qA##c.x, e##c##x, qA##c.y * e##c##y) +              \
           fmaf(qA##c.z, e##c##z, qA##c.w * e##c##w);
        CH(AC)
        WAVE_RED(dpp_addf, se)
        WAVE_RED(dpp_addf, sle)
        se  = rl63f(se);
        sle = rl63f(sle);

        const float inv = __builtin_amdgcn_rcpf(se);
        dcg = fmaf(__builtin_amdgcn_exp2f(sle * inv), INVDEN[k], dcg);

        // w' = w * (0.9 - e*inv)   [prod update folded into w]
#define UP(c)                                \
    w##c##x *= fmaf(e##c##x, -inv, 0.9f);    \
    w##c##y *= fmaf(e##c##y, -inv, 0.9f);    \
    w##c##z *= fmaf(e##c##z, -inv, 0.9f);    \
    w##c##w *= fmaf(e##c##w, -inv, 0.9f);
        CH(UP)
        M *= 0.9f;
    }

    if (lane == 0) {
        const float loss = 1.0f - dcg / idcg;
        if (mode) atomicAdd(out, loss);
        else      ws[row] = loss;
    }
}

__global__ __launch_bounds__(256) void reduce_sum_kernel(
    const float* __restrict__ w, float* __restrict__ out, int n4) {
    __shared__ float sb[4];
    float acc = 0.0f;
    const float4* w4 = (const float4*)w;
    for (int i = threadIdx.x; i < n4; i += 256) {
        const float4 v = w4[i];
        acc += (v.x + v.y) + (v.z + v.w);
    }
#pragma unroll
    for (int o = 32; o; o >>= 1) acc += __shfl_xor(acc, o, 64);
    if ((threadIdx.x & 63) == 0) sb[threadIdx.x >> 6] = acc;
    __syncthreads();
    if (threadIdx.x == 0) out[0] = (sb[0] + sb[1]) + (sb[2] + sb[3]);
}

__global__ void zero_out_kernel(float* out) { out[0] = 0.0f; }

extern "C" void kernel_launch(void* const* d_in, const int* in_sizes, int n_in,
                              void* d_out, int out_size, void* d_ws,
                              size_t ws_size, hipStream_t stream) {
    const float* s     = (const float*)d_in[0];
    const float* label = (const float*)d_in[1];
    float*       out   = (float*)d_out;
    const int    bs    = in_sizes[0] / LL;

    if ((bs % RPB) == 0 && ws_size >= (size_t)bs * sizeof(float)) {
        float* w = (float*)d_ws;
        ndcg_loss_kernel<<<bs / RPB, THREADS, 0, stream>>>(s, label, w, nullptr, 0);
        reduce_sum_kernel<<<1, 256, 0, stream>>>(w, out, bs / 4);
    } else {
        zero_out_kernel<<<1, 1, 0, stream>>>(out);
        ndcg_loss_kernel<<<bs / RPB, THREADS, 0, stream>>>(s, label, nullptr, out, 1);
    }
}